// Round 4
// baseline (166.862 us; speedup 1.0000x reference)
//
#include <hip/hip_runtime.h>
#include <math.h>

#define H 64
#define W 64
#define C 128
#define NB 8
#define COUT 128
#define HWi 4096
#define NKC2 18
#define PADu 40          // gemm27 LDS pitch (80B, conflict-free)
#define PB 72            // gemm128 B-tile pitch in ushorts (144B)

typedef __attribute__((ext_vector_type(8))) short short8;
typedef __attribute__((ext_vector_type(8))) unsigned short ushort8;
typedef __attribute__((ext_vector_type(4))) unsigned short ushort4v;
typedef __attribute__((ext_vector_type(4))) float f32x4;
typedef __attribute__((ext_vector_type(2))) float f32x2;

__device__ __forceinline__ unsigned short f2bf(float f){
    unsigned u = __float_as_uint(f);
    unsigned r = (u + 0x7FFFu + ((u >> 16) & 1u)) >> 16;
    return (unsigned short)r;
}
__device__ __forceinline__ float bf2f(unsigned short u){
    return __uint_as_float(((unsigned)u) << 16);
}
__device__ __forceinline__ f32x2 up2(unsigned p){
    f32x2 r;
    r.x = __uint_as_float(p << 16);
    r.y = __uint_as_float(p & 0xFFFF0000u);
    return r;
}
__device__ __forceinline__ unsigned pk2(f32x2 v){
    return (unsigned)f2bf(v.x) | ((unsigned)f2bf(v.y) << 16);
}

// ---------- k_pre: fused x-transpose + weight prep + psum zero ----------
// blocks [0,528): x NCHW fp32 -> zero-padded NHWC bf16 [8][66][66][128]
// blocks [528,1250): wA [kc36][oc128][kkl32] (kk=kc*32+kkl, k=kk>>7, c=kk&127),
//                    w27A [kc][m32][kk32], biasom, psum=0
__global__ void k_pre(const float* __restrict__ x, unsigned short* __restrict__ xTp,
                      const float* __restrict__ w_reg, const float* __restrict__ w_off,
                      const float* __restrict__ w_mod, const float* __restrict__ b_off,
                      const float* __restrict__ b_mod,
                      unsigned short* __restrict__ wA, unsigned short* __restrict__ w27A,
                      float* __restrict__ biasom, float* __restrict__ psum){
    int tid = threadIdx.x;
    if (blockIdx.x >= 528){
        int i = (blockIdx.x - 528) * 256 + tid;
        if (i < 147456){
            int kc = i >> 12, rem = i & 4095, oc = rem >> 5, kkl = rem & 31;
            int kk = kc * 32 + kkl, k = kk >> 7, c = kk & 127;
            wA[i] = f2bf(w_reg[oc * 1152 + c * 9 + k]);
        } else if (i < 147456 + 36864){
            int j2 = i - 147456;
            int kc = j2 >> 10, rem = j2 & 1023, m = rem >> 5, kkl = rem & 31;
            int kk = kc * 32 + kkl, k = kk >> 7, c = kk & 127;
            float v = 0.f;
            if (m < 18) v = w_off[m * 1152 + c * 9 + k];
            else if (m < 27) v = w_mod[(m - 18) * 1152 + c * 9 + k];
            w27A[j2] = f2bf(v);
        } else if (i < 147456 + 36864 + 32){
            int m = i - 147456 - 36864;
            biasom[m] = (m < 18) ? b_off[m] : (m < 27 ? b_mod[m - 18] : 0.f);
        } else if (i < 147456 + 36864 + 32 + 256){
            psum[i - 147456 - 36864 - 32] = 0.f;
        }
        return;
    }
    int bidx = blockIdx.x;
    int b = bidx / 66, hp = bidx - b * 66;
    unsigned short* row = xTp + (size_t)(b * 66 + hp) * 66 * 128;
    if (hp == 0 || hp == 65){
        ushort8 z = {0,0,0,0,0,0,0,0};
        for (int i = tid; i < 66 * 128 / 8; i += 256) ((ushort8*)row)[i] = z;
        return;
    }
    int h = hp - 1;
    __shared__ unsigned s2[64 * 69];   // bf16 pairs, pitch 69 dwords (stride-5 banks: free)
    int w = tid & 63, cp = tid >> 6;
    for (int cc = 0; cc < 16; cc++){
        int c2 = cc * 4 + cp;       // channel-pair index 0..63
        int c = c2 * 2;
        float f0 = x[(size_t)(b * 128 + c)     * HWi + h * 64 + w];
        float f1 = x[(size_t)(b * 128 + c + 1) * HWi + h * 64 + w];
        s2[w * 69 + c2] = (unsigned)f2bf(f0) | ((unsigned)f2bf(f1) << 16);
    }
    __syncthreads();
    if (tid < 32){
        ushort8 z = {0,0,0,0,0,0,0,0};
        int wp = (tid < 16) ? 0 : 65;
        int sg = tid & 15;
        *(ushort8*)(row + wp * 128 + sg * 8) = z;
    }
    for (int it = tid; it < 1024; it += 256){
        int w2 = it >> 4, sg = it & 15;
        uint4 v;
        v.x = s2[w2 * 69 + sg * 4 + 0];
        v.y = s2[w2 * 69 + sg * 4 + 1];
        v.z = s2[w2 * 69 + sg * 4 + 2];
        v.w = s2[w2 * 69 + sg * 4 + 3];
        *(uint4*)(row + (w2 + 1) * 128 + sg * 8) = v;
    }
}

// ---------- k_gemm27: offset+mod conv, MFMA, padded LDS, pipelined ----------
__global__ __launch_bounds__(256) void k_gemm27(const unsigned short* __restrict__ xTp,
        const unsigned short* __restrict__ w27A, const float* __restrict__ biasom,
        unsigned short* __restrict__ OM){
    __shared__ unsigned short sA[2][32 * PADu];
    __shared__ unsigned short sB[2][64 * PADu];
    int tid = threadIdx.x;
    int n0 = blockIdx.x * 64;
    int b = n0 >> 12, h = (n0 >> 6) & 63;
    int wv = tid >> 6, lane = tid & 63, quad = lane >> 4, l16 = lane & 15;
    int nl = tid >> 2, sg = tid & 3;
    f32x4 acc0 = {0.f,0.f,0.f,0.f}, acc1 = {0.f,0.f,0.f,0.f};

    ushort8 rA, rB;
    auto loadNext = [&](int kcn){
        int k = kcn >> 2, cb = (kcn & 3) << 5;
        int ki = k / 3, kj = k - ki * 3;
        if (tid < 128) rA = *(const ushort8*)(w27A + kcn * 1024 + tid * 8);
        int rowi = (b * 66 + h + ki) * 66 + (nl + kj);
        rB = *(const ushort8*)(xTp + (size_t)rowi * 128 + cb + sg * 8);
    };
    loadNext(0);
    for (int kc = 0; kc < 36; kc++){
        int p = kc & 1;
        if (tid < 128) *(ushort8*)(&sA[p][(tid >> 2) * PADu + (tid & 3) * 8]) = rA;
        *(ushort8*)(&sB[p][nl * PADu + sg * 8]) = rB;
        if (kc + 1 < 36) loadNext(kc + 1);
        __syncthreads();
        short8 bfrag = *(const short8*)(&sB[p][(wv * 16 + l16) * PADu + quad * 8]);
        short8 a0 = *(const short8*)(&sA[p][l16 * PADu + quad * 8]);
        short8 a1 = *(const short8*)(&sA[p][(16 + l16) * PADu + quad * 8]);
        acc0 = __builtin_amdgcn_mfma_f32_16x16x32_bf16(a0, bfrag, acc0, 0, 0, 0);
        acc1 = __builtin_amdgcn_mfma_f32_16x16x32_bf16(a1, bfrag, acc1, 0, 0, 0);
    }
    int n = n0 + wv * 16 + l16;
    #pragma unroll
    for (int t = 0; t < 2; t++){
        f32x4 a = t ? acc1 : acc0;
        ushort4v o;
        #pragma unroll
        for (int r = 0; r < 4; r++){
            int oc = t * 16 + quad * 4 + r;
            float v = a[r] + biasom[oc];
            if (oc >= 18) v = 2.f / (1.f + expf(-v));
            o[r] = f2bf(v);
        }
        *(ushort4v*)(OM + n * 32 + t * 16 + quad * 4) = o;
    }
}

// ---------- k_gemm128: deformable conv, BK=64, A direct from global, all-thread sampling ----------
__global__ __launch_bounds__(512, 4) void k_gemm128(const unsigned short* __restrict__ xTp,
        const unsigned short* __restrict__ OM, const unsigned short* __restrict__ wA,
        const float* __restrict__ b_reg, unsigned short* __restrict__ ybf,
        float* __restrict__ psum){
    __shared__ char smem[36864];
    // sB: [2][64*PB] ushorts = 18432 B ; s_a0: int[4][576] @18432 ; s_w0: float[4][576] @27648
    unsigned short* sB = (unsigned short*)smem;
    int*   s_a0 = (int*)(smem + 18432);
    float* s_w0 = (float*)(smem + 27648);

    int tid = threadIdx.x;
    int n0 = blockIdx.x * 64;
    int b = n0 >> 12, h = (n0 >> 6) & 63;

    for (int idx = tid; idx < 576; idx += 512){
        int k = idx >> 6, px = idx & 63;
        int n = n0 + px;
        float dy = bf2f(OM[n * 32 + 2 * k]);
        float dx = bf2f(OM[n * 32 + 2 * k + 1]);
        float m  = bf2f(OM[n * 32 + 18 + k]);
        int ki = k / 3, kj = k - ki * 3;
        float py  = (float)(h - 1 + ki) + dy;
        float pxf = (float)(px - 1 + kj) + dx;
        float y0f = floorf(py), x0f = floorf(pxf);
        float ly = py - y0f, lx = pxf - x0f;
        int iy0 = (int)y0f, ix0 = (int)x0f;
        int cy0 = min(max(iy0 + 1, 0), 65), cy1 = min(max(iy0 + 2, 0), 65);
        int cx0 = min(max(ix0 + 1, 0), 65), cx1 = min(max(ix0 + 2, 0), 65);
        int rb = b * 66 * 66;
        s_a0[0 * 576 + idx] = ((rb + cy0 * 66) + cx0) * 128;
        s_a0[1 * 576 + idx] = ((rb + cy0 * 66) + cx1) * 128;
        s_a0[2 * 576 + idx] = ((rb + cy1 * 66) + cx0) * 128;
        s_a0[3 * 576 + idx] = ((rb + cy1 * 66) + cx1) * 128;
        s_w0[0 * 576 + idx] = (1.f - ly) * (1.f - lx) * m;
        s_w0[1 * 576 + idx] = (1.f - ly) * lx * m;
        s_w0[2 * 576 + idx] = ly * (1.f - lx) * m;
        s_w0[3 * 576 + idx] = ly * lx * m;
    }
    __syncthreads();

    int wv = tid >> 6, lane = tid & 63, quad = lane >> 4, l16 = lane & 15;
    int ocq = wv & 3, ng = wv >> 2;
    int spx = tid & 63, cg = tid >> 6;

    f32x4 acc00 = {0.f,0.f,0.f,0.f}, acc01 = {0.f,0.f,0.f,0.f};
    f32x4 acc10 = {0.f,0.f,0.f,0.f}, acc11 = {0.f,0.f,0.f,0.f};

    ushort8 a00, a01, a10, a11;          // current A frags (h,t)
    ushort8 na00, na01, na10, na11;      // next
    ushort8 rc0, rc1, rc2, rc3;          // corner vectors
    float w0, w1, w2, w3;

    auto loadA = [&](int kc2, ushort8& x00, ushort8& x01, ushort8& x10, ushort8& x11){
        const unsigned short* b0 = wA + (kc2 * 2 + 0) * 4096 + quad * 8;
        const unsigned short* b1 = wA + (kc2 * 2 + 1) * 4096 + quad * 8;
        int r0 = (ocq * 32 + l16) * 32, r1 = (ocq * 32 + 16 + l16) * 32;
        x00 = *(const ushort8*)(b0 + r0);
        x10 = *(const ushort8*)(b0 + r1);
        x01 = *(const ushort8*)(b1 + r0);
        x11 = *(const ushort8*)(b1 + r1);
    };
    auto loadB = [&](int kc2){
        int k = kc2 >> 1, co = ((kc2 & 1) << 6) + cg * 8;
        int idx = k * 64 + spx;
        w0 = s_w0[idx]; w1 = s_w0[576 + idx]; w2 = s_w0[1152 + idx]; w3 = s_w0[1728 + idx];
        rc0 = *(const ushort8*)(xTp + s_a0[idx] + co);
        rc1 = *(const ushort8*)(xTp + s_a0[576 + idx] + co);
        rc2 = *(const ushort8*)(xTp + s_a0[1152 + idx] + co);
        rc3 = *(const ushort8*)(xTp + s_a0[1728 + idx] + co);
    };

    loadA(0, a00, a01, a10, a11);
    loadB(0);

    #pragma unroll 2
    for (int kc2 = 0; kc2 < NKC2; kc2++){
        int p = kc2 & 1;
        unsigned short* sBp = sB + p * (64 * PB);
        {   // sample 8 channels (float2 math -> pk ops), write 16B to LDS
            const unsigned* u0 = (const unsigned*)&rc0;
            const unsigned* u1 = (const unsigned*)&rc1;
            const unsigned* u2 = (const unsigned*)&rc2;
            const unsigned* u3 = (const unsigned*)&rc3;
            uint4 o;
            unsigned* op = (unsigned*)&o;
            #pragma unroll
            for (int j = 0; j < 4; j++){
                f32x2 v = w0 * up2(u0[j]);
                v += w1 * up2(u1[j]);
                v += w2 * up2(u2[j]);
                v += w3 * up2(u3[j]);
                op[j] = pk2(v);
            }
            *(uint4*)(sBp + spx * PB + cg * 8) = o;
        }
        if (kc2 + 1 < NKC2){
            loadA(kc2 + 1, na00, na01, na10, na11);
            loadB(kc2 + 1);
        }
        __syncthreads();
        int rb0 = (ng * 32 + l16) * PB + quad * 8;
        int rb1 = (ng * 32 + 16 + l16) * PB + quad * 8;
        short8 b00 = *(const short8*)(sBp + rb0);        // tn0,t0
        short8 b01 = *(const short8*)(sBp + rb0 + 32);   // tn0,t1
        short8 b10 = *(const short8*)(sBp + rb1);        // tn1,t0
        short8 b11 = *(const short8*)(sBp + rb1 + 32);   // tn1,t1
        acc00 = __builtin_amdgcn_mfma_f32_16x16x32_bf16(a00, b00, acc00, 0, 0, 0);
        acc00 = __builtin_amdgcn_mfma_f32_16x16x32_bf16(a01, b01, acc00, 0, 0, 0);
        acc01 = __builtin_amdgcn_mfma_f32_16x16x32_bf16(a00, b10, acc01, 0, 0, 0);
        acc01 = __builtin_amdgcn_mfma_f32_16x16x32_bf16(a01, b11, acc01, 0, 0, 0);
        acc10 = __builtin_amdgcn_mfma_f32_16x16x32_bf16(a10, b00, acc10, 0, 0, 0);
        acc10 = __builtin_amdgcn_mfma_f32_16x16x32_bf16(a11, b01, acc10, 0, 0, 0);
        acc11 = __builtin_amdgcn_mfma_f32_16x16x32_bf16(a10, b10, acc11, 0, 0, 0);
        acc11 = __builtin_amdgcn_mfma_f32_16x16x32_bf16(a11, b11, acc11, 0, 0, 0);
        a00 = na00; a01 = na01; a10 = na10; a11 = na11;
    }

    __syncthreads();
    float* ls = (float*)smem;   // [128][69] fp32 = 35328 B (reuses all tile memory)
    int sp0 = h * 64;
    #pragma unroll
    for (int to = 0; to < 2; to++){
        #pragma unroll
        for (int tn = 0; tn < 2; tn++){
            f32x4 a = to ? (tn ? acc11 : acc10) : (tn ? acc01 : acc00);
            int nl = ng * 32 + tn * 16 + l16;
            #pragma unroll
            for (int r = 0; r < 4; r++){
                int oc = ocq * 32 + to * 16 + quad * 4 + r;
                float v = a[r] + b_reg[oc];
                ybf[(size_t)(b * 128 + oc) * HWi + sp0 + nl] = f2bf(v);
                ls[oc * 69 + nl] = v;
            }
        }
    }
    __syncthreads();
    if (tid < 128){
        int oc = tid;
        float s = 0.f, s2 = 0.f;
        #pragma unroll 8
        for (int nl = 0; nl < 64; nl++){
            float v = ls[oc * 69 + nl];
            s += v; s2 = fmaf(v, v, s2);
        }
        atomicAdd(&psum[oc], s);
        atomicAdd(&psum[128 + oc], s2);
    }
}

// ---------- k_apply: BN (stats inline from psum) + affine + relu -> fp32 ----------
__global__ void k_apply(const unsigned short* __restrict__ ybf, const float* __restrict__ psum,
                        const float* __restrict__ gamma, const float* __restrict__ beta,
                        float* __restrict__ out){
    int e8 = (blockIdx.x * 256 + threadIdx.x) * 8;
    int c = (e8 >> 12) & 127;
    ushort8 u = *(const ushort8*)(ybf + e8);
    float s = psum[c], s2 = psum[128 + c];
    float mean = s * (1.f / 32768.f);
    float var  = s2 * (1.f / 32768.f) - mean * mean;
    float rs = rsqrtf(var + 1e-5f);
    float g = gamma[c] * rs;
    float bt = beta[c] - mean * g;
    float4 lo, hi;
    lo.x = fmaxf(fmaf(bf2f(u[0]), g, bt), 0.f);
    lo.y = fmaxf(fmaf(bf2f(u[1]), g, bt), 0.f);
    lo.z = fmaxf(fmaf(bf2f(u[2]), g, bt), 0.f);
    lo.w = fmaxf(fmaf(bf2f(u[3]), g, bt), 0.f);
    hi.x = fmaxf(fmaf(bf2f(u[4]), g, bt), 0.f);
    hi.y = fmaxf(fmaf(bf2f(u[5]), g, bt), 0.f);
    hi.z = fmaxf(fmaf(bf2f(u[6]), g, bt), 0.f);
    hi.w = fmaxf(fmaf(bf2f(u[7]), g, bt), 0.f);
    *(float4*)(out + e8)     = lo;
    *(float4*)(out + e8 + 4) = hi;
}

extern "C" void kernel_launch(void* const* d_in, const int* in_sizes, int n_in,
                              void* d_out, int out_size, void* d_ws, size_t ws_size,
                              hipStream_t stream){
    const float* x     = (const float*)d_in[0];
    const float* w_off = (const float*)d_in[1];
    const float* b_off = (const float*)d_in[2];
    const float* w_mod = (const float*)d_in[3];
    const float* b_mod = (const float*)d_in[4];
    const float* w_reg = (const float*)d_in[5];
    const float* b_reg = (const float*)d_in[6];
    const float* gamma = (const float*)d_in[7];
    const float* beta  = (const float*)d_in[8];

    char* wsb = (char*)d_ws;
    unsigned short* xTp   = (unsigned short*)(wsb);                    // 8,921,088 B
    unsigned short* OM    = (unsigned short*)(wsb + 8921088);          // 2,097,152 B
    unsigned short* ybf   = (unsigned short*)(wsb + 11018240);         // 8,388,608 B
    unsigned short* wA    = (unsigned short*)(wsb + 19406848);         //   294,912 B
    unsigned short* w27A  = (unsigned short*)(wsb + 19701760);         //    73,728 B
    float*          biasom= (float*)(wsb + 19775488);                  //       128 B
    float*          psum  = (float*)(wsb + 19775616);                  //     1,024 B
    float* out = (float*)d_out;

    hipLaunchKernelGGL(k_pre,    dim3(1250), dim3(256), 0, stream, x, xTp, w_reg, w_off, w_mod, b_off, b_mod, wA, w27A, biasom, psum);
    hipLaunchKernelGGL(k_gemm27, dim3(512),  dim3(256), 0, stream, xTp, w27A, biasom, OM);
    hipLaunchKernelGGL(k_gemm128,dim3(512),  dim3(512), 0, stream, xTp, OM, wA, b_reg, ybf, psum);
    hipLaunchKernelGGL(k_apply,  dim3(2048), dim3(256), 0, stream, ybf, psum, gamma, beta, out);
}